// Round 8
// baseline (356.943 us; speedup 1.0000x reference)
//
#include <hip/hip_runtime.h>
#include <hip/hip_bf16.h>
#include <math.h>

#define BDIM 512
#define DDIM 512
#define CDIM 100000
#define NC 64
#define NCHUNK ((CDIM + NC - 1) / NC)   // 1563
#define GRID 256                        // persistent blocks, 1/CU

typedef __attribute__((ext_vector_type(8))) short short8;
typedef __attribute__((ext_vector_type(4))) float f32x4;

__device__ __forceinline__ unsigned short f2bf(float f) {
  unsigned int u = __builtin_bit_cast(unsigned int, f);
  u = (u + 0x7FFFu + ((u >> 16) & 1u)) >> 16;   // RNE
  return (unsigned short)u;
}

// ---- kernel 1: L2-normalize feature rows, emit bf16 [B][D] ----
__global__ void k_rownorm(const float* __restrict__ x, unsigned short* __restrict__ a) {
  const int b = blockIdx.x;
  const int tid = threadIdx.x;
  const float* row = x + (size_t)b * DDIM;
  float v0 = row[tid], v1 = row[tid + 256];
  float ss = v0 * v0 + v1 * v1;
  #pragma unroll
  for (int m = 1; m < 64; m <<= 1) ss += __shfl_xor(ss, m);
  __shared__ float sred[4];
  __shared__ float sinv;
  if ((tid & 63) == 0) sred[tid >> 6] = ss;
  __syncthreads();
  if (tid == 0) {
    float s = sred[0] + sred[1] + sred[2] + sred[3];
    sinv = 1.f / fmaxf(sqrtf(s), 1e-12f);
  }
  __syncthreads();
  const float inv = sinv;
  a[(size_t)b * DDIM + tid] = f2bf(v0 * inv);
  a[(size_t)b * DDIM + tid + 256] = f2bf(v1 * inv);
}

// ---- kernel 2: fused colnorm + GEMM + margin + per-chunk LSE partials ----
// Producer/consumer wave specialization. 1024 threads:
//   waves 0-7  (t<512):  consumers — K-loop (af from L2-resident a, bfr from
//                        LDS), epilogue with per-chunk LSE partials.
//   waves 8-15 (t>=512): producers — stage chunk i+1's 64x512 fp32 w-slab
//                        (16 float4/thread in flight), cvt->bf16 into the
//                        other LDS buffer, column sumsq.
// vmcnt is PER-WAVE: producers' staging queue and consumers' af queue never
// couple -> staging latency/BW fully hidden under the K-loop. One
// __syncthreads per chunk. Double-buffered 2x64KB B + 2x2KB sumsq.
__global__ __launch_bounds__(1024, 4)
void k_main(const unsigned short* __restrict__ a,
            const float* __restrict__ w,
            const long long* __restrict__ label,
            float2* __restrict__ part,
            float* __restrict__ labellogit) {
  __shared__ __align__(16) unsigned short blds[2][NC][DDIM];  // 128 KB
  __shared__ float ssred[2][8][NC];                           // 4 KB

  const int t = threadIdx.x;
  const int bid = blockIdx.x;
  const int nloc = (NCHUNK - bid + GRID - 1) / GRID;   // >= 6

  if (t >= 512) {
    // ================= producers =================
    const int tp = t - 512;
    const int pw = tp >> 6;          // 0..7
    const int lane = tp & 63;
    const int c4 = (tp & 15) * 4;    // 4 cols
    const int tg = tp >> 4;          // 0..31: k-octet group
    float4 p[16];

    auto issue = [&](int sq) {
      const int chunk = bid + sq * GRID;
      const int c0 = chunk * NC;
      const bool tail = (c0 + NC > CDIM);
      #pragma unroll
      for (int h = 0; h < 2; h++)
        #pragma unroll
        for (int j = 0; j < 8; j++) {
          const int k = (tg + 32 * h) * 8 + j;
          const float* src = w + (size_t)k * CDIM + c0 + c4;
          if (!tail) {
            p[h * 8 + j] = *reinterpret_cast<const float4*>(src);
          } else {
            #pragma unroll
            for (int cc = 0; cc < 4; cc++)
              p[h * 8 + j][cc] = (c0 + c4 + cc < CDIM) ? src[cc] : 0.f;
          }
        }
    };
    auto commit = [&](int sq) {
      const int buf = sq & 1;
      float ss0 = 0.f, ss1 = 0.f, ss2 = 0.f, ss3 = 0.f;
      #pragma unroll
      for (int i = 0; i < 16; i++) {
        ss0 += p[i].x * p[i].x; ss1 += p[i].y * p[i].y;
        ss2 += p[i].z * p[i].z; ss3 += p[i].w * p[i].w;
      }
      #pragma unroll
      for (int h = 0; h < 2; h++)
        #pragma unroll
        for (int cc = 0; cc < 4; cc++) {
          const int c = c4 + cc;
          short8 v;
          #pragma unroll
          for (int j = 0; j < 8; j++) v[j] = (short)f2bf(p[h * 8 + j][cc]);
          *reinterpret_cast<short8*>(
              &blds[buf][c][((tg + 32 * h) * 8) ^ ((c & 7) << 3)]) = v;
        }
      #pragma unroll
      for (int msk = 16; msk < 64; msk <<= 1) {
        ss0 += __shfl_xor(ss0, msk);
        ss1 += __shfl_xor(ss1, msk);
        ss2 += __shfl_xor(ss2, msk);
        ss3 += __shfl_xor(ss3, msk);
      }
      if (lane < 16)
        *reinterpret_cast<float4*>(&ssred[buf][pw][c4]) = (float4){ss0, ss1, ss2, ss3};
    };

    issue(0);
    commit(0);
    if (nloc > 1) issue(1);
    __syncthreads();
    for (int sq = 0; sq < nloc; sq++) {
      if (sq + 1 < nloc) commit(sq + 1);   // vmcnt wait overlaps consumers' K-loop
      if (sq + 2 < nloc) issue(sq + 2);    // next loads in flight for a full iter
      __syncthreads();
    }
  } else {
    // ================= consumers =================
    const int wave = t >> 6;
    const int lane = t & 63;
    const int lhi = lane >> 4;   // 0..3
    const int llo = lane & 15;   // 0..15

    const unsigned short* ab0 = a + (size_t)(wave * 64 + 0 * 16 + llo) * DDIM + (lhi << 3);
    const unsigned short* ab1 = a + (size_t)(wave * 64 + 1 * 16 + llo) * DDIM + (lhi << 3);
    const unsigned short* ab2 = a + (size_t)(wave * 64 + 2 * 16 + llo) * DDIM + (lhi << 3);
    const unsigned short* ab3 = a + (size_t)(wave * 64 + 3 * 16 + llo) * DDIM + (lhi << 3);

    __syncthreads();
    for (int sq = 0; sq < nloc; sq++) {
      const int chunk = bid + sq * GRID;
      const int c0 = chunk * NC;
      const int buf = sq & 1;

      f32x4 acc[4][4];
      #pragma unroll
      for (int i = 0; i < 4; i++)
        #pragma unroll
        for (int j = 0; j < 4; j++)
          acc[i][j] = (f32x4){0.f, 0.f, 0.f, 0.f};

      #pragma unroll
      for (int step = 0; step < 16; step++) {
        const int koff = step * 32;
        short8 af[4], bfr[4];
        af[0] = *reinterpret_cast<const short8*>(ab0 + koff);
        af[1] = *reinterpret_cast<const short8*>(ab1 + koff);
        af[2] = *reinterpret_cast<const short8*>(ab2 + koff);
        af[3] = *reinterpret_cast<const short8*>(ab3 + koff);
        #pragma unroll
        for (int cf = 0; cf < 4; cf++) {
          const int c = cf * 16 + llo;
          bfr[cf] = *reinterpret_cast<const short8*>(
              &blds[buf][c][(koff + (lhi << 3)) ^ ((c & 7) << 3)]);
        }
        #pragma unroll
        for (int rf = 0; rf < 4; rf++)
          #pragma unroll
          for (int cf = 0; cf < 4; cf++)
            acc[rf][cf] = __builtin_amdgcn_mfma_f32_16x16x32_bf16(af[rf], bfr[cf], acc[rf][cf], 0, 0, 0);
      }

      // inverse column norms from producers' sumsq partials (sealed last barrier)
      float inv[4];
      #pragma unroll
      for (int cf = 0; cf < 4; cf++) {
        const int c = cf * 16 + llo;
        float s = 0.f;
        #pragma unroll
        for (int pw = 0; pw < 8; pw++) s += ssred[buf][pw][c];
        inv[cf] = 1.f / fmaxf(sqrtf(s), 1e-12f);
      }

      // epilogue: per-row (max, sumexp) partials over this chunk's 64 classes
      #pragma unroll
      for (int rf = 0; rf < 4; rf++) {
        #pragma unroll
        for (int r = 0; r < 4; r++) {
          const int row = wave * 64 + rf * 16 + (lhi << 2) + r;
          const int lab = (int)label[row];
          float vals[4];
          float mloc = -INFINITY;
          #pragma unroll
          for (int cf = 0; cf < 4; cf++) {
            const int cg = c0 + cf * 16 + llo;
            float cs = acc[rf][cf][r] * inv[cf];
            cs = fminf(fmaxf(cs, -1.f), 1.f);
            float lg = 64.f * cs;
            if (cg == lab) { lg = 64.f * (cs - 0.35f); labellogit[row] = lg; }
            if (cg >= CDIM) lg = -INFINITY;
            vals[cf] = lg;
            mloc = fmaxf(mloc, lg);
          }
          float m = mloc;
          #pragma unroll
          for (int msk = 1; msk < 16; msk <<= 1) m = fmaxf(m, __shfl_xor(m, msk));
          float s = 0.f;
          #pragma unroll
          for (int cf = 0; cf < 4; cf++) s += __expf(vals[cf] - m);
          #pragma unroll
          for (int msk = 1; msk < 16; msk <<= 1) s += __shfl_xor(s, msk);
          if (llo == 0) part[(size_t)chunk * BDIM + row] = make_float2(m, s);
        }
      }
      __syncthreads();
    }
  }
}

// ---- kernel 3: per-row online-LSE combine over chunks (part is [chunk][row]) ----
__global__ void k_rowreduce(const float2* __restrict__ part,
                            const float* __restrict__ labellogit,
                            float* __restrict__ rowloss) {
  const int row = blockIdx.x;
  const int tid = threadIdx.x;
  float m = -INFINITY, s = 0.f;
  for (int ch = tid; ch < NCHUNK; ch += 256) {
    float2 p = part[(size_t)ch * BDIM + row];
    float nm = fmaxf(m, p.x);
    s = s * __expf(m - nm) + p.y * __expf(p.x - nm);
    m = nm;
  }
  #pragma unroll
  for (int msk = 1; msk < 64; msk <<= 1) {
    float om = __shfl_xor(m, msk), os = __shfl_xor(s, msk);
    float nm = fmaxf(m, om);
    s = s * __expf(m - nm) + os * __expf(om - nm);
    m = nm;
  }
  __shared__ float sm[4], ssum[4];
  const int wv = tid >> 6, ln = tid & 63;
  if (ln == 0) { sm[wv] = m; ssum[wv] = s; }
  __syncthreads();
  if (tid == 0) {
    float M = sm[0], S = ssum[0];
    #pragma unroll
    for (int i = 1; i < 4; i++) {
      float nm = fmaxf(M, sm[i]);
      S = S * __expf(M - nm) + ssum[i] * __expf(sm[i] - nm);
      M = nm;
    }
    rowloss[row] = M + logf(S) - labellogit[row];
  }
}

// ---- kernel 4: mean over rows -> scalar ----
__global__ void k_mean(const float* __restrict__ rowloss, float* __restrict__ out) {
  const int tid = threadIdx.x;
  float v = rowloss[tid];
  #pragma unroll
  for (int msk = 1; msk < 64; msk <<= 1) v += __shfl_xor(v, msk);
  __shared__ float sred[8];
  if ((tid & 63) == 0) sred[tid >> 6] = v;
  __syncthreads();
  if (tid == 0) {
    float s = 0.f;
    #pragma unroll
    for (int i = 0; i < 8; i++) s += sred[i];
    out[0] = s / (float)BDIM;
  }
}

extern "C" void kernel_launch(void* const* d_in, const int* in_sizes, int n_in,
                              void* d_out, int out_size, void* d_ws, size_t ws_size,
                              hipStream_t stream) {
  const float* input = (const float*)d_in[0];
  const long long* label = (const long long*)d_in[1];
  const float* w = (const float*)d_in[2];
  float* out = (float*)d_out;

  char* ws = (char*)d_ws;
  // layout (bytes): a_bf16 @0 (512KB); part @524288 (1563*512*8);
  //                 labellogit @6926336; rowloss @6928384
  unsigned short* a_bf16 = (unsigned short*)(ws + 0);
  float2* part           = (float2*)(ws + 524288);
  float* labellogit      = (float*)(ws + 6926336);
  float* rowloss         = (float*)(ws + 6928384);

  k_rownorm<<<BDIM, 256, 0, stream>>>(input, a_bf16);
  k_main<<<GRID, 1024, 0, stream>>>(a_bf16, w, label, part, labellogit);
  k_rowreduce<<<BDIM, 256, 0, stream>>>(part, labellogit, rowloss);
  k_mean<<<1, BDIM, 0, stream>>>(rowloss, out);
}

// Round 10
// 224.724 us; speedup vs baseline: 1.5884x; 1.5884x over previous
//
#include <hip/hip_runtime.h>
#include <hip/hip_bf16.h>
#include <math.h>

#define BDIM 512
#define DDIM 512
#define CDIM 100000
#define NC 64
#define BM 256
#define BN 256
#define BK 64
#define NKSTEP (DDIM / BK)               // 8
#define GN 391                           // ceil(100000/256) col-blocks
#define CPADT (GN * BN)                  // 100096 padded classes
#define NCHT (CPADT / NC)                // 1564 chunks
#define CTILE 128                        // classes per k_wt block

typedef __attribute__((ext_vector_type(8))) short short8;
typedef __attribute__((ext_vector_type(4))) float f32x4;

__device__ __forceinline__ unsigned short f2bf(float f) {
  unsigned int u = __builtin_bit_cast(unsigned int, f);
  u = (u + 0x7FFFu + ((u >> 16) & 1u)) >> 16;   // RNE
  return (unsigned short)u;
}

__device__ __forceinline__ void gl_lds16(const unsigned short* g, unsigned short* l) {
  __builtin_amdgcn_global_load_lds(
      (const __attribute__((address_space(1))) void*)g,
      (__attribute__((address_space(3))) void*)l, 16, 0, 0);
}

// ---- kernel 1: L2-normalize feature rows, emit bf16 [B][D] ----
__global__ void k_rownorm(const float* __restrict__ x, unsigned short* __restrict__ a) {
  const int b = blockIdx.x;
  const int tid = threadIdx.x;
  const float* row = x + (size_t)b * DDIM;
  float v0 = row[tid], v1 = row[tid + 256];
  float ss = v0 * v0 + v1 * v1;
  #pragma unroll
  for (int m = 1; m < 64; m <<= 1) ss += __shfl_xor(ss, m);
  __shared__ float sred[4];
  __shared__ float sinv;
  if ((tid & 63) == 0) sred[tid >> 6] = ss;
  __syncthreads();
  if (tid == 0) {
    float s = sred[0] + sred[1] + sred[2] + sred[3];
    sinv = 1.f / fmaxf(sqrtf(s), 1e-12f);
  }
  __syncthreads();
  const float inv = sinv;
  a[(size_t)b * DDIM + tid] = f2bf(v0 * inv);
  a[(size_t)b * DDIM + tid + 256] = f2bf(v1 * inv);
}

// ---- kernel 1b: transpose+convert w [D][C] fp32 -> w_t [CPADT][D] bf16, + invwn ----
// Proven 4.5 TB/s streaming transpose. Pad classes [CDIM, CPADT) get zeros, invwn=1.
__global__ __launch_bounds__(512)
void k_wt(const float* __restrict__ w, unsigned short* __restrict__ wt,
          float* __restrict__ invwn) {
  __shared__ float tile[64][CTILE + 4];
  const int t = threadIdx.x;
  const int c0w = blockIdx.x * CTILE;
  const int rd_d = t >> 3;            // 0..63
  const int rd_c = (t & 7) * 16;      // col segment base
  const int wc = t >> 2;              // 0..127 class
  const int wh = t & 3;               // 0..3 d-quarter
  float ss = 0.f;

  for (int ch = 0; ch < 8; ch++) {
    const int d0 = ch * 64;
    float4 r[4];
    #pragma unroll
    for (int j = 0; j < 4; j++) {
      const int c = c0w + rd_c + j * 4;
      if (c + 3 < CDIM)
        r[j] = *reinterpret_cast<const float4*>(w + (size_t)(d0 + rd_d) * CDIM + c);
      else {
        #pragma unroll
        for (int e = 0; e < 4; e++)
          r[j][e] = (c + e < CDIM) ? w[(size_t)(d0 + rd_d) * CDIM + c + e] : 0.f;
      }
    }
    #pragma unroll
    for (int j = 0; j < 4; j++)
      *reinterpret_cast<float4*>(&tile[rd_d][rd_c + j * 4]) = r[j];
    __syncthreads();

    short8 o0, o1;
    #pragma unroll
    for (int j = 0; j < 8; j++) {
      const float v = tile[wh * 16 + j][wc];
      ss += v * v;
      o0[j] = (short)f2bf(v);
    }
    #pragma unroll
    for (int j = 0; j < 8; j++) {
      const float v = tile[wh * 16 + 8 + j][wc];
      ss += v * v;
      o1[j] = (short)f2bf(v);
    }
    {
      unsigned short* dst = wt + ((size_t)(c0w + wc) << 9) + d0 + wh * 16;
      *reinterpret_cast<short8*>(dst) = o0;       // pad classes get zeros
      *reinterpret_cast<short8*>(dst + 8) = o1;
    }
    __syncthreads();
  }
  ss += __shfl_xor(ss, 1);
  ss += __shfl_xor(ss, 2);
  if (wh == 0)
    invwn[c0w + wc] = (c0w + wc < CDIM) ? 1.f / fmaxf(sqrtf(ss), 1e-12f) : 1.f;
}

// ---- kernel 2: 256x256 tiled GEMM + margin + per-chunk LSE partials ----
// BM=BN=256, BK=64, double-buffered LDS (128 KB), 8 waves = 2(row) x 4(col),
// per-wave 128x64 output (acc[8][4]). A AND B staged via global_load_lds with
// pre-swizzled sources (rule #21); K-loop has ZERO global loads -> the
// barrier's vmcnt drain is exactly the wait-for-next-stage.
__global__ __launch_bounds__(512, 2)
void k_main(const unsigned short* __restrict__ a,
            const unsigned short* __restrict__ wt,
            const float* __restrict__ invwn,
            const long long* __restrict__ label,
            float2* __restrict__ part,
            float* __restrict__ labellogit) {
  __shared__ __align__(16) unsigned short alds[2][BM * BK];   // 2 x 32 KB
  __shared__ __align__(16) unsigned short blds[2][BN * BK];   // 2 x 32 KB

  const int t = threadIdx.x;
  const int blkm = blockIdx.x & 1;
  const int blkn = blockIdx.x >> 1;          // adjacent pair shares B (L3-warm)
  const int bm0 = blkm * BM;
  const int bn0 = blkn * BN;

  const int wave = t >> 6;                   // 0..7
  const int lane = t & 63;
  const int wr = wave >> 2;                  // 0..1 row-half
  const int wc = wave & 3;                   // 0..3 col-quarter
  const int lhi = lane >> 4;                 // 0..3
  const int llo = lane & 15;                 // 0..15
  const int l8 = lane & 7;

  // staging: wave stages rows [wave*32, wave*32+32) of A and of B per K-step,
  // 4 gl_lds16 each; source piece pre-swizzled by row&7 so linear LDS dest
  // yields swizzled layout (read piece = want ^ (row&7)).
  auto stage = [&](int s, int buf) {
    #pragma unroll
    for (int i = 0; i < 4; i++) {
      const int row = wave * 32 + i * 8 + (lane >> 3);
      const int piece = l8 ^ (row & 7);
      gl_lds16(a + (size_t)(bm0 + row) * DDIM + s * BK + piece * 8,
               &alds[buf][(wave * 32 + i * 8) * BK]);
      gl_lds16(wt + ((size_t)(bn0 + row) << 9) + s * BK + piece * 8,
               &blds[buf][(wave * 32 + i * 8) * BK]);
    }
  };

  f32x4 acc[8][4];
  #pragma unroll
  for (int i = 0; i < 8; i++)
    #pragma unroll
    for (int j = 0; j < 4; j++)
      acc[i][j] = (f32x4){0.f, 0.f, 0.f, 0.f};

  stage(0, 0);
  __syncthreads();                            // drains vmcnt (stage arrived)

  int buf = 0;
  #pragma unroll
  for (int s = 0; s < NKSTEP; s++) {
    if (s + 1 < NKSTEP) stage(s + 1, buf ^ 1);

    #pragma unroll
    for (int kk = 0; kk < 2; kk++) {
      const int pc = (kk * 4 + lhi) ^ l8;     // swizzled 16B piece
      short8 af[8], bfr[4];
      #pragma unroll
      for (int m = 0; m < 8; m++) {
        const int row = wr * 128 + m * 16 + llo;
        af[m] = *reinterpret_cast<const short8*>(&alds[buf][row * BK + pc * 8]);
      }
      #pragma unroll
      for (int n = 0; n < 4; n++) {
        const int col = wc * 64 + n * 16 + llo;
        bfr[n] = *reinterpret_cast<const short8*>(&blds[buf][col * BK + pc * 8]);
      }
      #pragma unroll
      for (int m = 0; m < 8; m++)
        #pragma unroll
        for (int n = 0; n < 4; n++)
          acc[m][n] = __builtin_amdgcn_mfma_f32_16x16x32_bf16(af[m], bfr[n], acc[m][n], 0, 0, 0);
    }

    __syncthreads();                          // drains vmcnt: next stage ready
    buf ^= 1;
  }

  // ---- epilogue ----
  float inv[4];
  #pragma unroll
  for (int n = 0; n < 4; n++)
    inv[n] = invwn[bn0 + wc * 64 + n * 16 + llo];

  const int chunk = blkn * 4 + wc;            // this wave's 64-col chunk
  #pragma unroll
  for (int m = 0; m < 8; m++) {
    #pragma unroll
    for (int r = 0; r < 4; r++) {
      const int row = bm0 + wr * 128 + m * 16 + (lhi << 2) + r;
      const int lab = (int)label[row];
      float vals[4];
      // Finite lower bound (< min possible logit -86.4). An all-pad lane or
      // all-pad chunk (chunk 1563: classes 100032..100095 all >= CDIM) would
      // otherwise give mm=-inf and exp(-inf - -inf)=NaN.
      float mloc = -100.0f;
      #pragma unroll
      for (int n = 0; n < 4; n++) {
        const int cg = bn0 + wc * 64 + n * 16 + llo;
        float cs = acc[m][n][r] * inv[n];
        cs = fminf(fmaxf(cs, -1.f), 1.f);
        float lg = 64.f * cs;
        if (cg == lab) { lg = 64.f * (cs - 0.35f); labellogit[row] = lg; }
        if (cg >= CDIM) lg = -INFINITY;
        vals[n] = lg;
        mloc = fmaxf(mloc, lg);
      }
      float mm = mloc;
      #pragma unroll
      for (int msk = 1; msk < 16; msk <<= 1) mm = fmaxf(mm, __shfl_xor(mm, msk));
      float sacc = 0.f;
      #pragma unroll
      for (int n = 0; n < 4; n++) sacc += __expf(vals[n] - mm);   // exp(-inf-mm)=0
      #pragma unroll
      for (int msk = 1; msk < 16; msk <<= 1) sacc += __shfl_xor(sacc, msk);
      if (llo == 0) part[(size_t)chunk * BDIM + row] = make_float2(mm, sacc);
    }
  }
}

// ---- kernel 3: per-row online-LSE combine over chunks (part is [chunk][row]) ----
__global__ void k_rowreduce(const float2* __restrict__ part,
                            const float* __restrict__ labellogit,
                            float* __restrict__ rowloss) {
  const int row = blockIdx.x;
  const int tid = threadIdx.x;
  float m = -INFINITY, s = 0.f;
  for (int ch = tid; ch < NCHT; ch += 256) {
    float2 p = part[(size_t)ch * BDIM + row];
    float nm = fmaxf(m, p.x);
    s = s * __expf(m - nm) + p.y * __expf(p.x - nm);
    m = nm;
  }
  #pragma unroll
  for (int msk = 1; msk < 64; msk <<= 1) {
    float om = __shfl_xor(m, msk), os = __shfl_xor(s, msk);
    float nm = fmaxf(m, om);
    s = s * __expf(m - nm) + os * __expf(om - nm);
    m = nm;
  }
  __shared__ float sm[4], ssum[4];
  const int wv = tid >> 6, ln = tid & 63;
  if (ln == 0) { sm[wv] = m; ssum[wv] = s; }
  __syncthreads();
  if (tid == 0) {
    float M = sm[0], S = ssum[0];
    #pragma unroll
    for (int i = 1; i < 4; i++) {
      float nm = fmaxf(M, sm[i]);
      S = S * __expf(M - nm) + ssum[i] * __expf(sm[i] - nm);
      M = nm;
    }
    rowloss[row] = M + logf(S) - labellogit[row];
  }
}

// ---- kernel 4: mean over rows -> scalar ----
__global__ void k_mean(const float* __restrict__ rowloss, float* __restrict__ out) {
  const int tid = threadIdx.x;
  float v = rowloss[tid];
  #pragma unroll
  for (int msk = 1; msk < 64; msk <<= 1) v += __shfl_xor(v, msk);
  __shared__ float sred[8];
  if ((tid & 63) == 0) sred[tid >> 6] = v;
  __syncthreads();
  if (tid == 0) {
    float s = 0.f;
    #pragma unroll
    for (int i = 0; i < 8; i++) s += sred[i];
    out[0] = s / (float)BDIM;
  }
}

extern "C" void kernel_launch(void* const* d_in, const int* in_sizes, int n_in,
                              void* d_out, int out_size, void* d_ws, size_t ws_size,
                              hipStream_t stream) {
  const float* input = (const float*)d_in[0];
  const long long* label = (const long long*)d_in[1];
  const float* w = (const float*)d_in[2];
  float* out = (float*)d_out;

  char* ws = (char*)d_ws;
  // layout (bytes):
  //   a_bf16     @ 0         524288
  //   part       @ 524288    1564*512*8 = 6406144   (ends 6930432)
  //   labellogit @ 6930432   2048
  //   rowloss    @ 6932480   2048
  //   invwn      @ 6934528   100096*4 = 400384      (ends 7334912)
  //   w_t        @ 7334912   100096*512*2 = 102498304
  unsigned short* a_bf16 = (unsigned short*)(ws + 0);
  float2* part           = (float2*)(ws + 524288);
  float* labellogit      = (float*)(ws + 6930432);
  float* rowloss         = (float*)(ws + 6932480);
  float* invwn           = (float*)(ws + 6934528);
  unsigned short* w_t    = (unsigned short*)(ws + 7334912);

  k_rownorm<<<BDIM, 256, 0, stream>>>(input, a_bf16);
  k_wt<<<CPADT / CTILE, 512, 0, stream>>>(w, w_t, invwn);
  k_main<<<2 * GN, 512, 0, stream>>>(a_bf16, w_t, invwn, label, part, labellogit);
  k_rowreduce<<<BDIM, 256, 0, stream>>>(part, labellogit, rowloss);
  k_mean<<<1, BDIM, 0, stream>>>(rowloss, out);
}

// Round 11
// 176.171 us; speedup vs baseline: 2.0261x; 1.2756x over previous
//
#include <hip/hip_runtime.h>
#include <hip/hip_bf16.h>
#include <math.h>

#define BDIM 512
#define DDIM 512
#define CDIM 100000
#define NC 64
#define BM 128
#define BN 128
#define BK 64
#define NKSTEP (DDIM / BK)               // 8
#define GNB 782                          // col-blocks of 128 (100096/128)
#define CPADT 100096                     // padded classes
#define NCHT (CPADT / NC)                // 1564 chunks
#define NBLK (GNB * 4)                   // 3128 blocks (4 row-blocks)
#define CTILE 128                        // classes per k_wt block

typedef __attribute__((ext_vector_type(8))) short short8;
typedef __attribute__((ext_vector_type(4))) float f32x4;

__device__ __forceinline__ unsigned short f2bf(float f) {
  unsigned int u = __builtin_bit_cast(unsigned int, f);
  u = (u + 0x7FFFu + ((u >> 16) & 1u)) >> 16;   // RNE
  return (unsigned short)u;
}

__device__ __forceinline__ void gl_lds16(const unsigned short* g, unsigned short* l) {
  __builtin_amdgcn_global_load_lds(
      (const __attribute__((address_space(1))) void*)g,
      (__attribute__((address_space(3))) void*)l, 16, 0, 0);
}

// ---- kernel 1: L2-normalize feature rows, emit bf16 [B][D] ----
__global__ void k_rownorm(const float* __restrict__ x, unsigned short* __restrict__ a) {
  const int b = blockIdx.x;
  const int tid = threadIdx.x;
  const float* row = x + (size_t)b * DDIM;
  float v0 = row[tid], v1 = row[tid + 256];
  float ss = v0 * v0 + v1 * v1;
  #pragma unroll
  for (int m = 1; m < 64; m <<= 1) ss += __shfl_xor(ss, m);
  __shared__ float sred[4];
  __shared__ float sinv;
  if ((tid & 63) == 0) sred[tid >> 6] = ss;
  __syncthreads();
  if (tid == 0) {
    float s = sred[0] + sred[1] + sred[2] + sred[3];
    sinv = 1.f / fmaxf(sqrtf(s), 1e-12f);
  }
  __syncthreads();
  const float inv = sinv;
  a[(size_t)b * DDIM + tid] = f2bf(v0 * inv);
  a[(size_t)b * DDIM + tid + 256] = f2bf(v1 * inv);
}

// ---- kernel 1b: transpose+convert w [D][C] fp32 -> w_t [CPADT][D] bf16, + invwn ----
// Proven ~6 TB/s streaming transpose (4+ blocks/CU). Pad classes get zeros, invwn=1.
__global__ __launch_bounds__(512)
void k_wt(const float* __restrict__ w, unsigned short* __restrict__ wt,
          float* __restrict__ invwn) {
  __shared__ float tile[64][CTILE + 4];
  const int t = threadIdx.x;
  const int c0w = blockIdx.x * CTILE;
  const int rd_d = t >> 3;            // 0..63
  const int rd_c = (t & 7) * 16;      // col segment base
  const int wc = t >> 2;              // 0..127 class
  const int wh = t & 3;               // 0..3 d-quarter
  float ss = 0.f;

  for (int ch = 0; ch < 8; ch++) {
    const int d0 = ch * 64;
    float4 r[4];
    #pragma unroll
    for (int j = 0; j < 4; j++) {
      const int c = c0w + rd_c + j * 4;
      if (c + 3 < CDIM)
        r[j] = *reinterpret_cast<const float4*>(w + (size_t)(d0 + rd_d) * CDIM + c);
      else {
        #pragma unroll
        for (int e = 0; e < 4; e++)
          r[j][e] = (c + e < CDIM) ? w[(size_t)(d0 + rd_d) * CDIM + c + e] : 0.f;
      }
    }
    #pragma unroll
    for (int j = 0; j < 4; j++)
      *reinterpret_cast<float4*>(&tile[rd_d][rd_c + j * 4]) = r[j];
    __syncthreads();

    short8 o0, o1;
    #pragma unroll
    for (int j = 0; j < 8; j++) {
      const float v = tile[wh * 16 + j][wc];
      ss += v * v;
      o0[j] = (short)f2bf(v);
    }
    #pragma unroll
    for (int j = 0; j < 8; j++) {
      const float v = tile[wh * 16 + 8 + j][wc];
      ss += v * v;
      o1[j] = (short)f2bf(v);
    }
    {
      unsigned short* dst = wt + ((size_t)(c0w + wc) << 9) + d0 + wh * 16;
      *reinterpret_cast<short8*>(dst) = o0;       // pad classes get zeros
      *reinterpret_cast<short8*>(dst + 8) = o1;
    }
    __syncthreads();
  }
  ss += __shfl_xor(ss, 1);
  ss += __shfl_xor(ss, 2);
  if (wh == 0)
    invwn[c0w + wc] = (c0w + wc < CDIM) ? 1.f / fmaxf(sqrtf(ss), 1e-12f) : 1.f;
}

// ---- kernel 2: 128x128 tiled GEMM + margin + per-chunk LSE partials ----
// 256 threads / 4 waves, single-buffered 32 KB LDS -> 4 independent
// barrier-domains per CU (the k_wt regime that sustains ~6 TB/s).
// R10's verified zero-conflict (row&7) piece swizzle for staging + reads.
// XCD-swizzled grid: 4 row-siblings of each col-band adjacent on one XCD.
__global__ __launch_bounds__(256, 4)
void k_main(const unsigned short* __restrict__ a,
            const unsigned short* __restrict__ wt,
            const float* __restrict__ invwn,
            const long long* __restrict__ label,
            float2* __restrict__ part,
            float* __restrict__ labellogit) {
  __shared__ __align__(16) unsigned short alds[BM * BK];   // 16 KB
  __shared__ __align__(16) unsigned short blds[BN * BK];   // 16 KB

  const int t = threadIdx.x;
  // bijective XCD swizzle: NBLK % 8 == 0 (3128 = 8*391)
  const int orig = (blockIdx.x & 7) * (NBLK / 8) + (blockIdx.x >> 3);
  const int rb = orig & 3;                   // row-block 0..3
  const int cb = orig >> 2;                  // col-block 0..781
  const int bm0 = rb * BM;
  const int bn0 = cb * BN;

  const int wave = t >> 6;                   // 0..3
  const int lane = t & 63;
  const int wr = wave >> 1;                  // 0..1 row-half
  const int wc = wave & 1;                   // 0..1 col-half (= chunk within cb)
  const int lhi = lane >> 4;                 // 0..3
  const int llo = lane & 15;                 // 0..15
  const int l8 = lane & 7;

  // staging: wave stages rows [wave*32, wave*32+32) of A and of B per K-step;
  // source piece pre-swizzled by row&7 (row&7 == lane>>3), linear LDS dest.
  auto stage = [&](int s) {
    #pragma unroll
    for (int i = 0; i < 4; i++) {
      const int row = wave * 32 + i * 8 + (lane >> 3);
      const int piece = l8 ^ (lane >> 3);
      gl_lds16(a + (size_t)(bm0 + row) * DDIM + s * BK + piece * 8,
               &alds[(wave * 32 + i * 8) * BK]);
      gl_lds16(wt + ((size_t)(bn0 + row) << 9) + s * BK + piece * 8,
               &blds[(wave * 32 + i * 8) * BK]);
    }
  };

  f32x4 acc[4][4];
  #pragma unroll
  for (int i = 0; i < 4; i++)
    #pragma unroll
    for (int j = 0; j < 4; j++)
      acc[i][j] = (f32x4){0.f, 0.f, 0.f, 0.f};

  #pragma unroll
  for (int s = 0; s < NKSTEP; s++) {
    stage(s);
    __syncthreads();                          // vmcnt(0): staged tile arrived

    #pragma unroll
    for (int kk = 0; kk < 2; kk++) {
      short8 af[4], bfr[4];
      #pragma unroll
      for (int m = 0; m < 4; m++) {
        const int row = wr * 64 + m * 16 + llo;
        const int pc = (kk * 4 + lhi) ^ (row & 7);
        af[m] = *reinterpret_cast<const short8*>(&alds[row * BK + pc * 8]);
      }
      #pragma unroll
      for (int n = 0; n < 4; n++) {
        const int col = wc * 64 + n * 16 + llo;
        const int pc = (kk * 4 + lhi) ^ (col & 7);
        bfr[n] = *reinterpret_cast<const short8*>(&blds[col * BK + pc * 8]);
      }
      #pragma unroll
      for (int m = 0; m < 4; m++)
        #pragma unroll
        for (int n = 0; n < 4; n++)
          acc[m][n] = __builtin_amdgcn_mfma_f32_16x16x32_bf16(af[m], bfr[n], acc[m][n], 0, 0, 0);
    }

    __syncthreads();                          // protect single buffer
  }

  // ---- epilogue ----
  float inv[4];
  #pragma unroll
  for (int n = 0; n < 4; n++)
    inv[n] = invwn[bn0 + wc * 64 + n * 16 + llo];

  const int chunk = cb * 2 + wc;              // this wave's 64-col chunk
  #pragma unroll
  for (int m = 0; m < 4; m++) {
    #pragma unroll
    for (int r = 0; r < 4; r++) {
      const int row = bm0 + wr * 64 + m * 16 + (lhi << 2) + r;
      const int lab = (int)label[row];
      float vals[4];
      // finite floor (< min logit -86.4) so all-pad chunks give exp(-inf)=0, no NaN
      float mloc = -100.0f;
      #pragma unroll
      for (int n = 0; n < 4; n++) {
        const int cg = bn0 + wc * 64 + n * 16 + llo;
        float cs = acc[m][n][r] * inv[n];
        cs = fminf(fmaxf(cs, -1.f), 1.f);
        float lg = 64.f * cs;
        if (cg == lab) { lg = 64.f * (cs - 0.35f); labellogit[row] = lg; }
        if (cg >= CDIM) lg = -INFINITY;
        vals[n] = lg;
        mloc = fmaxf(mloc, lg);
      }
      float mm = mloc;
      #pragma unroll
      for (int msk = 1; msk < 16; msk <<= 1) mm = fmaxf(mm, __shfl_xor(mm, msk));
      float sacc = 0.f;
      #pragma unroll
      for (int n = 0; n < 4; n++) sacc += __expf(vals[n] - mm);
      #pragma unroll
      for (int msk = 1; msk < 16; msk <<= 1) sacc += __shfl_xor(sacc, msk);
      if (llo == 0) part[(size_t)chunk * BDIM + row] = make_float2(mm, sacc);
    }
  }
}

// ---- kernel 3: per-row online-LSE combine over chunks (part is [chunk][row]) ----
__global__ void k_rowreduce(const float2* __restrict__ part,
                            const float* __restrict__ labellogit,
                            float* __restrict__ rowloss) {
  const int row = blockIdx.x;
  const int tid = threadIdx.x;
  float m = -INFINITY, s = 0.f;
  for (int ch = tid; ch < NCHT; ch += 256) {
    float2 p = part[(size_t)ch * BDIM + row];
    float nm = fmaxf(m, p.x);
    s = s * __expf(m - nm) + p.y * __expf(p.x - nm);
    m = nm;
  }
  #pragma unroll
  for (int msk = 1; msk < 64; msk <<= 1) {
    float om = __shfl_xor(m, msk), os = __shfl_xor(s, msk);
    float nm = fmaxf(m, om);
    s = s * __expf(m - nm) + os * __expf(om - nm);
    m = nm;
  }
  __shared__ float sm[4], ssum[4];
  const int wv = tid >> 6, ln = tid & 63;
  if (ln == 0) { sm[wv] = m; ssum[wv] = s; }
  __syncthreads();
  if (tid == 0) {
    float M = sm[0], S = ssum[0];
    #pragma unroll
    for (int i = 1; i < 4; i++) {
      float nm = fmaxf(M, sm[i]);
      S = S * __expf(M - nm) + ssum[i] * __expf(sm[i] - nm);
      M = nm;
    }
    rowloss[row] = M + logf(S) - labellogit[row];
  }
}

// ---- kernel 4: mean over rows -> scalar ----
__global__ void k_mean(const float* __restrict__ rowloss, float* __restrict__ out) {
  const int tid = threadIdx.x;
  float v = rowloss[tid];
  #pragma unroll
  for (int msk = 1; msk < 64; msk <<= 1) v += __shfl_xor(v, msk);
  __shared__ float sred[8];
  if ((tid & 63) == 0) sred[tid >> 6] = v;
  __syncthreads();
  if (tid == 0) {
    float s = 0.f;
    #pragma unroll
    for (int i = 0; i < 8; i++) s += sred[i];
    out[0] = s / (float)BDIM;
  }
}

extern "C" void kernel_launch(void* const* d_in, const int* in_sizes, int n_in,
                              void* d_out, int out_size, void* d_ws, size_t ws_size,
                              hipStream_t stream) {
  const float* input = (const float*)d_in[0];
  const long long* label = (const long long*)d_in[1];
  const float* w = (const float*)d_in[2];
  float* out = (float*)d_out;

  char* ws = (char*)d_ws;
  // layout (bytes):
  //   a_bf16     @ 0         524288
  //   part       @ 524288    1564*512*8 = 6406144   (ends 6930432)
  //   labellogit @ 6930432   2048
  //   rowloss    @ 6932480   2048
  //   invwn      @ 6934528   100096*4 = 400384      (ends 7334912)
  //   w_t        @ 7334912   100096*512*2 = 102498304
  unsigned short* a_bf16 = (unsigned short*)(ws + 0);
  float2* part           = (float2*)(ws + 524288);
  float* labellogit      = (float*)(ws + 6930432);
  float* rowloss         = (float*)(ws + 6932480);
  float* invwn           = (float*)(ws + 6934528);
  unsigned short* w_t    = (unsigned short*)(ws + 7334912);

  k_rownorm<<<BDIM, 256, 0, stream>>>(input, a_bf16);
  k_wt<<<CPADT / CTILE, 512, 0, stream>>>(w, w_t, invwn);
  k_main<<<NBLK, 256, 0, stream>>>(a_bf16, w_t, invwn, label, part, labellogit);
  k_rowreduce<<<BDIM, 256, 0, stream>>>(part, labellogit, rowloss);
  k_mean<<<1, BDIM, 0, stream>>>(rowloss, out);
}